// Round 1
// baseline (869.232 us; speedup 1.0000x reference)
//
#include <hip/hip_runtime.h>
#include <hip/hip_bf16.h>
#include <math.h>

typedef short short8 __attribute__((ext_vector_type(8)));
typedef float f32x4 __attribute__((ext_vector_type(4)));

#define T_TOK 4096
#define D_DIM 1024
#define E_NUM 8
#define F_DIM 4096

#define BT 64      // token-tile
#define BN 64      // output-col tile
#define BK 32      // k-step
#define LPAD 8     // LDS row pad (elements)

__device__ __forceinline__ short f2bf(float f) {
  unsigned u = __builtin_bit_cast(unsigned, f);
  u = (u + 0x7FFFu + ((u >> 16) & 1u)) >> 16;
  return (short)u;
}

// ---------------- Router: fp64-accurate gates + top-2 ----------------
__global__ __launch_bounds__(64) void router_kernel(
    const float* __restrict__ x, const float* __restrict__ Wg,
    const float* __restrict__ bg,
    int* __restrict__ texp, float* __restrict__ tgate, int* __restrict__ cnt) {
  int t = blockIdx.x;
  int lane = threadIdx.x;
  double acc[E_NUM];
#pragma unroll
  for (int e = 0; e < E_NUM; ++e) acc[e] = 0.0;
  const float* xr = x + (size_t)t * D_DIM;
  for (int d = lane; d < D_DIM; d += 64) {
    double xv = (double)xr[d];
#pragma unroll
    for (int e = 0; e < E_NUM; ++e) acc[e] += xv * (double)Wg[d * E_NUM + e];
  }
#pragma unroll
  for (int off = 32; off > 0; off >>= 1) {
#pragma unroll
    for (int e = 0; e < E_NUM; ++e) acc[e] += __shfl_down(acc[e], off);
  }
  if (lane == 0) {
    double lg[E_NUM];
    double m = -1e300;
#pragma unroll
    for (int e = 0; e < E_NUM; ++e) {
      lg[e] = acc[e] + (double)bg[e];
      m = fmax(m, lg[e]);
    }
    double s = 0.0;
#pragma unroll
    for (int e = 0; e < E_NUM; ++e) { lg[e] = exp(lg[e] - m); s += lg[e]; }
    int e0 = 0; double g0 = lg[0];
#pragma unroll
    for (int e = 1; e < E_NUM; ++e) if (lg[e] > g0) { g0 = lg[e]; e0 = e; }
    int e1 = -1; double g1 = -1.0;
#pragma unroll
    for (int e = 0; e < E_NUM; ++e)
      if (e != e0 && lg[e] > g1) { g1 = lg[e]; e1 = e; }
    texp[2 * t]     = e0;
    texp[2 * t + 1] = e1;
    tgate[2 * t]     = (float)(g0 / s);
    tgate[2 * t + 1] = (float)(g1 / s);
    atomicAdd(&cnt[e0], 1);
    atomicAdd(&cnt[e1], 1);
  }
}

__global__ void offsets_kernel(const int* __restrict__ cnt,
                               int* __restrict__ off, int* __restrict__ cur) {
  if (threadIdx.x == 0 && blockIdx.x == 0) {
    int o = 0;
    for (int e = 0; e < E_NUM; ++e) { off[e] = o; cur[e] = o; o += cnt[e]; }
    off[E_NUM] = o;
  }
}

__global__ __launch_bounds__(256) void assign_kernel(
    const int* __restrict__ texp, const float* __restrict__ tgate,
    int* __restrict__ cur, int* __restrict__ tok_of, float* __restrict__ gate_of) {
  int t = blockIdx.x * 256 + threadIdx.x;
  if (t >= T_TOK) return;
#pragma unroll
  for (int k = 0; k < 2; ++k) {
    int e = texp[2 * t + k];
    int s = atomicAdd(&cur[e], 1);
    tok_of[s] = t;
    gate_of[s] = tgate[2 * t + k];
  }
}

// ---------------- Grouped GEMM1: h = relu(x @ W1 + b1), bf16 out ----------------
__global__ __launch_bounds__(256) void gemm1_kernel(
    const float* __restrict__ x, const float* __restrict__ W1,
    const float* __restrict__ b1,
    const int* __restrict__ off, const int* __restrict__ cnt,
    const int* __restrict__ tok_of, unsigned short* __restrict__ h) {
  int e = blockIdx.z;
  int count = cnt[e];
  int ty = blockIdx.y;
  if (ty * BT >= count) return;
  int f0 = blockIdx.x * BN;
  int base = off[e] + ty * BT;

  __shared__ short xs[BT][BK + LPAD];
  __shared__ short wst[BN][BK + LPAD];
  __shared__ int toks[BT];

  int tid = threadIdx.x;
  int lane = tid & 63;
  int wid = tid >> 6;
  int wr = wid >> 1, wc = wid & 1;

  if (tid < BT) {
    int idx = ty * BT + tid;
    toks[tid] = tok_of[(idx < count) ? (base + tid) : off[e]];
  }

  f32x4 acc[2][2];
#pragma unroll
  for (int r = 0; r < 2; ++r)
#pragma unroll
    for (int c = 0; c < 2; ++c) acc[r][c] = (f32x4){0.f, 0.f, 0.f, 0.f};

  int r_x = tid >> 2, k_x = (tid & 3) * 8;
  int k_w = tid >> 3, f_w = (tid & 7) * 8;
  const size_t w1base = (size_t)e * D_DIM * F_DIM;

  for (int k0 = 0; k0 < D_DIM; k0 += BK) {
    __syncthreads();
    {
      const float* px = x + (size_t)toks[r_x] * D_DIM + k0 + k_x;
      float4 v0 = *(const float4*)px;
      float4 v1 = *(const float4*)(px + 4);
      short8 pk;
      pk[0] = f2bf(v0.x); pk[1] = f2bf(v0.y); pk[2] = f2bf(v0.z); pk[3] = f2bf(v0.w);
      pk[4] = f2bf(v1.x); pk[5] = f2bf(v1.y); pk[6] = f2bf(v1.z); pk[7] = f2bf(v1.w);
      *(short8*)&xs[r_x][k_x] = pk;
    }
    {
      const float* pw = W1 + w1base + (size_t)(k0 + k_w) * F_DIM + f0 + f_w;
      float4 v0 = *(const float4*)pw;
      float4 v1 = *(const float4*)(pw + 4);
      float vv[8] = {v0.x, v0.y, v0.z, v0.w, v1.x, v1.y, v1.z, v1.w};
#pragma unroll
      for (int j = 0; j < 8; ++j) wst[f_w + j][k_w] = f2bf(vv[j]);
    }
    __syncthreads();
    int rr = lane & 15;
    int kf = (lane >> 4) * 8;
    short8 a0 = *(const short8*)&xs[wr * 32 + rr][kf];
    short8 a1 = *(const short8*)&xs[wr * 32 + 16 + rr][kf];
    short8 b0 = *(const short8*)&wst[wc * 32 + rr][kf];
    short8 b1v = *(const short8*)&wst[wc * 32 + 16 + rr][kf];
    acc[0][0] = __builtin_amdgcn_mfma_f32_16x16x32_bf16(a0, b0, acc[0][0], 0, 0, 0);
    acc[0][1] = __builtin_amdgcn_mfma_f32_16x16x32_bf16(a0, b1v, acc[0][1], 0, 0, 0);
    acc[1][0] = __builtin_amdgcn_mfma_f32_16x16x32_bf16(a1, b0, acc[1][0], 0, 0, 0);
    acc[1][1] = __builtin_amdgcn_mfma_f32_16x16x32_bf16(a1, b1v, acc[1][1], 0, 0, 0);
  }

  int col = lane & 15;
  int rowb = (lane >> 4) * 4;
#pragma unroll
  for (int r = 0; r < 2; ++r)
#pragma unroll
    for (int c = 0; c < 2; ++c)
#pragma unroll
      for (int i = 0; i < 4; ++i) {
        int rl = wr * 32 + r * 16 + rowb + i;
        if (ty * BT + rl < count) {
          int f = f0 + wc * 32 + c * 16 + col;
          float v = acc[r][c][i] + b1[e * F_DIM + f];
          v = fmaxf(v, 0.f);
          h[(size_t)(base + rl) * F_DIM + f] = (unsigned short)f2bf(v);
        }
      }
}

// ---------------- Grouped GEMM2: out[tok] += gate * (h @ W2 + b2) ----------------
__global__ __launch_bounds__(256) void gemm2_kernel(
    const unsigned short* __restrict__ h, const float* __restrict__ W2,
    const float* __restrict__ b2,
    const int* __restrict__ off, const int* __restrict__ cnt,
    const int* __restrict__ tok_of, const float* __restrict__ gate_of,
    float* __restrict__ out) {
  int e = blockIdx.z;
  int count = cnt[e];
  int ty = blockIdx.y;
  if (ty * BT >= count) return;
  int d0 = blockIdx.x * BN;
  int base = off[e] + ty * BT;

  __shared__ short hs[BT][BK + LPAD];
  __shared__ short wst[BN][BK + LPAD];

  int tid = threadIdx.x;
  int lane = tid & 63;
  int wid = tid >> 6;
  int wr = wid >> 1, wc = wid & 1;

  int r_x = tid >> 2, k_x = (tid & 3) * 8;
  int k_w = tid >> 3, d_w = (tid & 7) * 8;

  int srow_idx = ty * BT + r_x;
  size_t srow = (size_t)((srow_idx < count) ? (base + r_x) : off[e]);

  f32x4 acc[2][2];
#pragma unroll
  for (int r = 0; r < 2; ++r)
#pragma unroll
    for (int c = 0; c < 2; ++c) acc[r][c] = (f32x4){0.f, 0.f, 0.f, 0.f};

  const size_t w2base = (size_t)e * F_DIM * D_DIM;

  for (int k0 = 0; k0 < F_DIM; k0 += BK) {
    __syncthreads();
    {
      const unsigned short* ph = h + srow * F_DIM + k0 + k_x;
      short8 pk = *(const short8*)ph;
      *(short8*)&hs[r_x][k_x] = pk;
    }
    {
      const float* pw = W2 + w2base + (size_t)(k0 + k_w) * D_DIM + d0 + d_w;
      float4 v0 = *(const float4*)pw;
      float4 v1 = *(const float4*)(pw + 4);
      float vv[8] = {v0.x, v0.y, v0.z, v0.w, v1.x, v1.y, v1.z, v1.w};
#pragma unroll
      for (int j = 0; j < 8; ++j) wst[d_w + j][k_w] = f2bf(vv[j]);
    }
    __syncthreads();
    int rr = lane & 15;
    int kf = (lane >> 4) * 8;
    short8 a0 = *(const short8*)&hs[wr * 32 + rr][kf];
    short8 a1 = *(const short8*)&hs[wr * 32 + 16 + rr][kf];
    short8 b0 = *(const short8*)&wst[wc * 32 + rr][kf];
    short8 b1v = *(const short8*)&wst[wc * 32 + 16 + rr][kf];
    acc[0][0] = __builtin_amdgcn_mfma_f32_16x16x32_bf16(a0, b0, acc[0][0], 0, 0, 0);
    acc[0][1] = __builtin_amdgcn_mfma_f32_16x16x32_bf16(a0, b1v, acc[0][1], 0, 0, 0);
    acc[1][0] = __builtin_amdgcn_mfma_f32_16x16x32_bf16(a1, b0, acc[1][0], 0, 0, 0);
    acc[1][1] = __builtin_amdgcn_mfma_f32_16x16x32_bf16(a1, b1v, acc[1][1], 0, 0, 0);
  }

  int col = lane & 15;
  int rowb = (lane >> 4) * 4;
#pragma unroll
  for (int r = 0; r < 2; ++r)
#pragma unroll
    for (int c = 0; c < 2; ++c)
#pragma unroll
      for (int i = 0; i < 4; ++i) {
        int rl = wr * 32 + r * 16 + rowb + i;
        if (ty * BT + rl < count) {
          int slot = base + rl;
          int d = d0 + wc * 32 + c * 16 + col;
          float v = acc[r][c][i] + b2[e * D_DIM + d];
          v *= gate_of[slot];
          atomicAdd(&out[(size_t)tok_of[slot] * D_DIM + d], v);
        }
      }
}

extern "C" void kernel_launch(void* const* d_in, const int* in_sizes, int n_in,
                              void* d_out, int out_size, void* d_ws, size_t ws_size,
                              hipStream_t stream) {
  const float* x  = (const float*)d_in[0];
  const float* Wg = (const float*)d_in[1];
  const float* bg = (const float*)d_in[2];
  const float* W1 = (const float*)d_in[3];
  const float* b1 = (const float*)d_in[4];
  const float* W2 = (const float*)d_in[5];
  const float* b2 = (const float*)d_in[6];
  float* out = (float*)d_out;

  char* ws = (char*)d_ws;
  int*   cnt     = (int*)(ws + 0);
  int*   cur     = (int*)(ws + 64);
  int*   off     = (int*)(ws + 128);
  int*   texp    = (int*)(ws + 256);                       // 2*T ints
  float* tgate   = (float*)(ws + 256 + 2 * T_TOK * 4);     // 2*T floats
  int*   tok_of  = (int*)(ws + 256 + 4 * T_TOK * 4);       // 2*T ints
  float* gate_of = (float*)(ws + 256 + 6 * T_TOK * 4);     // 2*T floats
  unsigned short* h = (unsigned short*)(ws + 262144);      // 2*T x F bf16 = 64 MiB

  hipMemsetAsync(d_ws, 0, 256, stream);
  hipMemsetAsync(d_out, 0, (size_t)out_size * sizeof(float), stream);

  router_kernel<<<T_TOK, 64, 0, stream>>>(x, Wg, bg, texp, tgate, cnt);
  offsets_kernel<<<1, 64, 0, stream>>>(cnt, off, cur);
  assign_kernel<<<(T_TOK + 255) / 256, 256, 0, stream>>>(texp, tgate, cur, tok_of, gate_of);
  gemm1_kernel<<<dim3(F_DIM / BN, T_TOK / BT, E_NUM), 256, 0, stream>>>(
      x, W1, b1, off, cnt, tok_of, h);
  gemm2_kernel<<<dim3(D_DIM / BN, T_TOK / BT, E_NUM), 256, 0, stream>>>(
      h, W2, b2, off, cnt, tok_of, gate_of, out);
}

// Round 2
// 474.372 us; speedup vs baseline: 1.8324x; 1.8324x over previous
//
#include <hip/hip_runtime.h>
#include <hip/hip_bf16.h>
#include <math.h>

typedef short short8 __attribute__((ext_vector_type(8)));
typedef short s4v __attribute__((ext_vector_type(4)));
typedef float f32x4 __attribute__((ext_vector_type(4)));

#define T_TOK 4096
#define D_DIM 1024
#define E_NUM 8
#define F_DIM 4096
#define NSLOT (2 * T_TOK)

#define BM 128
#define BN 128
#define BK 32

__device__ __forceinline__ short f2bf(float f) {
  unsigned u = __builtin_bit_cast(unsigned, f);
  u = (u + 0x7FFFu + ((u >> 16) & 1u)) >> 16;
  return (short)u;
}

__device__ __forceinline__ void gload_lds16(unsigned short* lds, const unsigned short* g) {
  __builtin_amdgcn_global_load_lds(
      (const __attribute__((address_space(1))) unsigned int*)g,
      (__attribute__((address_space(3))) unsigned int*)lds, 16, 0, 0);
}

// ---------------- Router: fp64-accurate gates + top-2 ----------------
__global__ __launch_bounds__(64) void router_kernel(
    const float* __restrict__ x, const float* __restrict__ Wg,
    const float* __restrict__ bg,
    int* __restrict__ texp, float* __restrict__ tgate, int* __restrict__ cnt) {
  int t = blockIdx.x;
  int lane = threadIdx.x;
  double acc[E_NUM];
#pragma unroll
  for (int e = 0; e < E_NUM; ++e) acc[e] = 0.0;
  const float* xr = x + (size_t)t * D_DIM;
  for (int d = lane; d < D_DIM; d += 64) {
    double xv = (double)xr[d];
#pragma unroll
    for (int e = 0; e < E_NUM; ++e) acc[e] += xv * (double)Wg[d * E_NUM + e];
  }
#pragma unroll
  for (int off = 32; off > 0; off >>= 1) {
#pragma unroll
    for (int e = 0; e < E_NUM; ++e) acc[e] += __shfl_down(acc[e], off);
  }
  if (lane == 0) {
    double lg[E_NUM];
    double m = -1e300;
#pragma unroll
    for (int e = 0; e < E_NUM; ++e) {
      lg[e] = acc[e] + (double)bg[e];
      m = fmax(m, lg[e]);
    }
    double s = 0.0;
#pragma unroll
    for (int e = 0; e < E_NUM; ++e) { lg[e] = exp(lg[e] - m); s += lg[e]; }
    int e0 = 0; double g0 = lg[0];
#pragma unroll
    for (int e = 1; e < E_NUM; ++e) if (lg[e] > g0) { g0 = lg[e]; e0 = e; }
    int e1 = -1; double g1 = -1.0;
#pragma unroll
    for (int e = 0; e < E_NUM; ++e)
      if (e != e0 && lg[e] > g1) { g1 = lg[e]; e1 = e; }
    texp[2 * t]     = e0;
    texp[2 * t + 1] = e1;
    tgate[2 * t]     = (float)(g0 / s);
    tgate[2 * t + 1] = (float)(g1 / s);
    atomicAdd(&cnt[e0], 1);
    atomicAdd(&cnt[e1], 1);
  }
}

__global__ void offsets_kernel(const int* __restrict__ cnt,
                               int* __restrict__ off, int* __restrict__ cur) {
  if (threadIdx.x == 0 && blockIdx.x == 0) {
    int o = 0;
    for (int e = 0; e < E_NUM; ++e) { off[e] = o; cur[e] = o; o += cnt[e]; }
    off[E_NUM] = o;
  }
}

__global__ __launch_bounds__(256) void assign_kernel(
    const int* __restrict__ texp, const float* __restrict__ tgate,
    int* __restrict__ cur, int* __restrict__ tok_of, float* __restrict__ gate_of) {
  int t = blockIdx.x * 256 + threadIdx.x;
  if (t >= T_TOK) return;
#pragma unroll
  for (int k = 0; k < 2; ++k) {
    int e = texp[2 * t + k];
    int s = atomicAdd(&cur[e], 1);
    tok_of[s] = t;
    gate_of[s] = tgate[2 * t + k];
  }
}

// ---------------- x fp32 -> bf16 ----------------
__global__ __launch_bounds__(256) void xconv_kernel(
    const float* __restrict__ x, unsigned short* __restrict__ xb) {
  int i = blockIdx.x * 256 + threadIdx.x;  // one float4 each
  float4 v = ((const float4*)x)[i];
  s4v o;
  o[0] = f2bf(v.x); o[1] = f2bf(v.y); o[2] = f2bf(v.z); o[3] = f2bf(v.w);
  *(s4v*)&xb[(size_t)i * 4] = o;
}

// ---------------- per-expert [R][C] fp32 -> [C][R] bf16 ----------------
__global__ __launch_bounds__(256) void tconv_kernel(
    const float* __restrict__ in, unsigned short* __restrict__ out, int R, int C) {
  __shared__ float tile[64][65];
  int e = blockIdx.z;
  const float* ine = in + (size_t)e * R * C;
  unsigned short* oute = out + (size_t)e * R * C;
  int c0 = blockIdx.x * 64, r0 = blockIdx.y * 64;
  int tid = threadIdx.x;
  int lr = tid >> 4;           // 0..15
  int lc = (tid & 15) * 4;     // 0..60
#pragma unroll
  for (int p = 0; p < 4; ++p) {
    int row = p * 16 + lr;
    float4 v = *(const float4*)&ine[(size_t)(r0 + row) * C + c0 + lc];
    tile[row][lc] = v.x; tile[row][lc + 1] = v.y;
    tile[row][lc + 2] = v.z; tile[row][lc + 3] = v.w;
  }
  __syncthreads();
#pragma unroll
  for (int p = 0; p < 4; ++p) {
    int crow = p * 16 + lr;    // output row = original column
    s4v o;
#pragma unroll
    for (int j = 0; j < 4; ++j) o[j] = f2bf(tile[lc + j][crow]);
    *(s4v*)&oute[(size_t)(c0 + crow) * R + r0 + lc] = o;
  }
}

// ---------------- Grouped GEMM1: h = relu(xb @ W1 + b1), bf16 ----------------
__global__ __launch_bounds__(256) void gemm1_kernel(
    const unsigned short* __restrict__ xb, const unsigned short* __restrict__ w1t,
    const float* __restrict__ b1,
    const int* __restrict__ off, const int* __restrict__ cnt,
    const int* __restrict__ tok_of, unsigned short* __restrict__ h) {
  int e = blockIdx.z;
  int count = cnt[e];
  int ty = blockIdx.y;
  if (ty * BM >= count) return;
  int f0 = blockIdx.x * BN;
  int base = off[e] + ty * BM;

  __shared__ unsigned short As[BM][BK];  // 8 KB, linear
  __shared__ unsigned short Bs[BN][BK];  // 8 KB, linear

  int tid = threadIdx.x;
  int lane = tid & 63;
  int wid = tid >> 6;
  int wr = wid >> 1, wc = wid & 1;

  // staging: chunk c = r*4+wid covers rows c*16..c*16+15; lane l -> row c*16+(l>>2), col8 (l&3)*8
  const unsigned short* aga[2];
  const unsigned short* bga[2];
  unsigned short* alds[2];
  unsigned short* blds[2];
  const unsigned short* w1e = w1t + (size_t)e * F_DIM * D_DIM;
#pragma unroll
  for (int r = 0; r < 2; ++r) {
    int row = r * 64 + wid * 16 + (lane >> 2);
    int idx = ty * BM + row;
    int tok = tok_of[(idx < count) ? (base + row) : off[e]];
    aga[r] = xb + (size_t)tok * D_DIM + (lane & 3) * 8;
    bga[r] = w1e + (size_t)(f0 + row) * D_DIM + (lane & 3) * 8;
    alds[r] = &As[0][0] + (r * 4 + wid) * 512;
    blds[r] = &Bs[0][0] + (r * 4 + wid) * 512;
  }

  f32x4 acc[4][4];
#pragma unroll
  for (int m = 0; m < 4; ++m)
#pragma unroll
    for (int n = 0; n < 4; ++n) acc[m][n] = (f32x4){0.f, 0.f, 0.f, 0.f};

  for (int k0 = 0; k0 < D_DIM; k0 += BK) {
    __syncthreads();
    gload_lds16(alds[0], aga[0] + k0);
    gload_lds16(alds[1], aga[1] + k0);
    gload_lds16(blds[0], bga[0] + k0);
    gload_lds16(blds[1], bga[1] + k0);
    __syncthreads();
    int rr = lane & 15, kf = (lane >> 4) * 8;
    short8 af[4], bf[4];
#pragma unroll
    for (int m = 0; m < 4; ++m) af[m] = *(const short8*)&As[wr * 64 + m * 16 + rr][kf];
#pragma unroll
    for (int n = 0; n < 4; ++n) bf[n] = *(const short8*)&Bs[wc * 64 + n * 16 + rr][kf];
#pragma unroll
    for (int m = 0; m < 4; ++m)
#pragma unroll
      for (int n = 0; n < 4; ++n)
        acc[m][n] = __builtin_amdgcn_mfma_f32_16x16x32_bf16(af[m], bf[n], acc[m][n], 0, 0, 0);
  }

  int col = lane & 15, rowb = (lane >> 4) * 4;
#pragma unroll
  for (int m = 0; m < 4; ++m)
#pragma unroll
    for (int i = 0; i < 4; ++i) {
      int rl = wr * 64 + m * 16 + rowb + i;
      if (ty * BM + rl < count) {
        int slot = base + rl;
#pragma unroll
        for (int n = 0; n < 4; ++n) {
          int f = f0 + wc * 64 + n * 16 + col;
          float v = acc[m][n][i] + b1[e * F_DIM + f];
          h[(size_t)slot * F_DIM + f] = (unsigned short)f2bf(fmaxf(v, 0.f));
        }
      }
    }
}

// ---------------- Grouped GEMM2: out[tok] += gate * (h @ W2 + b2) ----------------
__global__ __launch_bounds__(256) void gemm2_kernel(
    const unsigned short* __restrict__ h, const unsigned short* __restrict__ w2t,
    const float* __restrict__ b2,
    const int* __restrict__ off, const int* __restrict__ cnt,
    const int* __restrict__ tok_of, const float* __restrict__ gate_of,
    float* __restrict__ out) {
  int e = blockIdx.z;
  int count = cnt[e];
  int ty = blockIdx.y;
  if (ty * BM >= count) return;
  int d0 = blockIdx.x * BN;
  int base = off[e] + ty * BM;

  __shared__ unsigned short As[BM][BK];
  __shared__ unsigned short Bs[BN][BK];

  int tid = threadIdx.x;
  int lane = tid & 63;
  int wid = tid >> 6;
  int wr = wid >> 1, wc = wid & 1;

  const unsigned short* aga[2];
  const unsigned short* bga[2];
  unsigned short* alds[2];
  unsigned short* blds[2];
  const unsigned short* w2e = w2t + (size_t)e * D_DIM * F_DIM;
#pragma unroll
  for (int r = 0; r < 2; ++r) {
    int row = r * 64 + wid * 16 + (lane >> 2);
    int arow = base + row;
    if (arow > NSLOT - 1) arow = NSLOT - 1;
    aga[r] = h + (size_t)arow * F_DIM + (lane & 3) * 8;
    bga[r] = w2e + (size_t)(d0 + row) * F_DIM + (lane & 3) * 8;
    alds[r] = &As[0][0] + (r * 4 + wid) * 512;
    blds[r] = &Bs[0][0] + (r * 4 + wid) * 512;
  }

  f32x4 acc[4][4];
#pragma unroll
  for (int m = 0; m < 4; ++m)
#pragma unroll
    for (int n = 0; n < 4; ++n) acc[m][n] = (f32x4){0.f, 0.f, 0.f, 0.f};

  for (int k0 = 0; k0 < F_DIM; k0 += BK) {
    __syncthreads();
    gload_lds16(alds[0], aga[0] + k0);
    gload_lds16(alds[1], aga[1] + k0);
    gload_lds16(blds[0], bga[0] + k0);
    gload_lds16(blds[1], bga[1] + k0);
    __syncthreads();
    int rr = lane & 15, kf = (lane >> 4) * 8;
    short8 af[4], bf[4];
#pragma unroll
    for (int m = 0; m < 4; ++m) af[m] = *(const short8*)&As[wr * 64 + m * 16 + rr][kf];
#pragma unroll
    for (int n = 0; n < 4; ++n) bf[n] = *(const short8*)&Bs[wc * 64 + n * 16 + rr][kf];
#pragma unroll
    for (int m = 0; m < 4; ++m)
#pragma unroll
      for (int n = 0; n < 4; ++n)
        acc[m][n] = __builtin_amdgcn_mfma_f32_16x16x32_bf16(af[m], bf[n], acc[m][n], 0, 0, 0);
  }

  int col = lane & 15, rowb = (lane >> 4) * 4;
#pragma unroll
  for (int m = 0; m < 4; ++m)
#pragma unroll
    for (int i = 0; i < 4; ++i) {
      int rl = wr * 64 + m * 16 + rowb + i;
      if (ty * BM + rl < count) {
        int slot = base + rl;
        int tok = tok_of[slot];
        float g = gate_of[slot];
#pragma unroll
        for (int n = 0; n < 4; ++n) {
          int d = d0 + wc * 64 + n * 16 + col;
          float v = acc[m][n][i] + b2[e * D_DIM + d];
          atomicAdd(&out[(size_t)tok * D_DIM + d], g * v);
        }
      }
    }
}

extern "C" void kernel_launch(void* const* d_in, const int* in_sizes, int n_in,
                              void* d_out, int out_size, void* d_ws, size_t ws_size,
                              hipStream_t stream) {
  const float* x  = (const float*)d_in[0];
  const float* Wg = (const float*)d_in[1];
  const float* bg = (const float*)d_in[2];
  const float* W1 = (const float*)d_in[3];
  const float* b1 = (const float*)d_in[4];
  const float* W2 = (const float*)d_in[5];
  const float* b2 = (const float*)d_in[6];
  float* out = (float*)d_out;

  char* ws = (char*)d_ws;
  int*   cnt     = (int*)(ws + 0);
  int*   cur     = (int*)(ws + 256);
  int*   off     = (int*)(ws + 512);
  int*   texp    = (int*)(ws + 1024);                       // 2T ints (32 KB)
  float* tgate   = (float*)(ws + 1024 + NSLOT * 4);         // 32 KB
  int*   tok_of  = (int*)(ws + 1024 + NSLOT * 8);           // 32 KB
  float* gate_of = (float*)(ws + 1024 + NSLOT * 12);        // 32 KB
  size_t o_xb   = 256 * 1024;
  size_t o_wt   = o_xb + (size_t)T_TOK * D_DIM * 2;                 // +8 MB
  size_t o_h    = o_wt + (size_t)E_NUM * D_DIM * F_DIM * 2;        // +64 MB
  unsigned short* xb  = (unsigned short*)(ws + o_xb);
  unsigned short* wt  = (unsigned short*)(ws + o_wt);   // w1t, later reused as w2t
  unsigned short* h   = (unsigned short*)(ws + o_h);    // 64 MB

  hipMemsetAsync(ws, 0, 256, stream);
  hipMemsetAsync(d_out, 0, (size_t)out_size * sizeof(float), stream);

  router_kernel<<<T_TOK, 64, 0, stream>>>(x, Wg, bg, texp, tgate, cnt);
  offsets_kernel<<<1, 64, 0, stream>>>(cnt, off, cur);
  assign_kernel<<<(T_TOK + 255) / 256, 256, 0, stream>>>(texp, tgate, cur, tok_of, gate_of);

  xconv_kernel<<<(T_TOK * D_DIM / 4) / 256, 256, 0, stream>>>(x, xb);
  // W1 [e][D][F] -> w1t [e][F][D]
  tconv_kernel<<<dim3(F_DIM / 64, D_DIM / 64, E_NUM), 256, 0, stream>>>(W1, wt, D_DIM, F_DIM);
  gemm1_kernel<<<dim3(F_DIM / BN, NSLOT / BM, E_NUM), 256, 0, stream>>>(
      xb, wt, b1, off, cnt, tok_of, h);
  // W2 [e][F][D] -> w2t [e][D][F]  (reuses wt)
  tconv_kernel<<<dim3(D_DIM / 64, F_DIM / 64, E_NUM), 256, 0, stream>>>(W2, wt, F_DIM, D_DIM);
  gemm2_kernel<<<dim3(D_DIM / BN, NSLOT / BM, E_NUM), 256, 0, stream>>>(
      h, wt, b2, off, cnt, tok_of, gate_of, out);
}